// Round 1
// baseline (1344.785 us; speedup 1.0000x reference)
//
#include <hip/hip_runtime.h>
#include <hip/hip_bf16.h>
#include <math.h>

// Problem constants (fixed by the reference setup):
//   E = 1,000,000 edges, N = 50,000 nodes, R = 6, H = 128, D = 256, C = 1, L = 3
#define H_DIM 128
#define R_DIM 6
#define D_DIM 256
#define L_NUM 3

// ---------------------------------------------------------------------------
// Stage 1: per-edge gate + scatter-add into node accumulator.
//   h[e, :] = (rbf[e, :] @ W_rbf^T) * x[e, :]   then   agg[i[e], :] += h[e, :]
// Layout: 256 threads = 2 edges x 128 h-columns; 8 edges per block.
// ---------------------------------------------------------------------------
__global__ __launch_bounds__(256) void edge_scatter_kernel(
    const float* __restrict__ x, const float* __restrict__ rbf,
    const int* __restrict__ idx, const float* __restrict__ W_rbf,
    float* __restrict__ agg, int E)
{
    __shared__ float sW[H_DIM * R_DIM];  // W_rbf is [H, R] row-major
    for (int t = threadIdx.x; t < H_DIM * R_DIM; t += 256) sW[t] = W_rbf[t];
    __syncthreads();

    const int h    = threadIdx.x & (H_DIM - 1);
    const int esub = threadIdx.x >> 7;       // 0..1
    const int ebase = blockIdx.x * 8;

    const float* wrow = &sW[h * R_DIM];

#pragma unroll
    for (int it = 0; it < 4; ++it) {
        const int e = ebase + it * 2 + esub;
        if (e < E) {
            const float* re = rbf + (size_t)e * R_DIM;
            float g = re[0] * wrow[0] + re[1] * wrow[1] + re[2] * wrow[2]
                    + re[3] * wrow[3] + re[4] * wrow[4] + re[5] * wrow[5];
            float v = g * x[(size_t)e * H_DIM + h];
            atomicAdd(&agg[(size_t)idx[e] * H_DIM + h], v);
        }
    }
}

// ---------------------------------------------------------------------------
// Stage 2: fp32 tiled GEMM  C[n, d] = sum_k A[n, k] * W[d, k]  (+bias, +SiLU)
//   A: [Nrows, K] row-major, W: [Dout, K] row-major (torch Linear layout).
// 64x64 tile, 256 threads, 4x4 register micro-tile, BK=16.
// LDS tiles stored transposed ([k][m]) so the inner loop uses ds_read_b128.
// ---------------------------------------------------------------------------
__global__ __launch_bounds__(256) void gemm_tn_kernel(
    const float* __restrict__ A, const float* __restrict__ W,
    const float* __restrict__ bias, float* __restrict__ C,
    int Nrows, int K, int Dout, int apply_silu)
{
    __shared__ __align__(16) float As[16][68];  // [k][m], stride 68 floats = 272 B (16B-mult)
    __shared__ __align__(16) float Bs[16][68];  // [k][d]

    const int tid = threadIdx.x;         // 0..255
    const int tx  = tid & 15;            // column group
    const int ty  = tid >> 4;            // row group
    const int row0 = blockIdx.x * 64;
    const int col0 = blockIdx.y * 64;

    // staging-load decomposition: thread -> (r, kq)
    const int lr  = tid >> 2;            // 0..63
    const int lkq = (tid & 3) * 4;       // 0,4,8,12

    float acc[4][4] = {};

    for (int k0 = 0; k0 < K; k0 += 16) {
        // A tile: 64 rows x 16 k, float4 along k, store transposed.
        {
            int rr = row0 + lr;
            if (rr > Nrows - 1) rr = Nrows - 1;     // clamp (re-read last row; stores masked)
            const float4 va = *(const float4*)(A + (size_t)rr * K + k0 + lkq);
            As[lkq + 0][lr] = va.x; As[lkq + 1][lr] = va.y;
            As[lkq + 2][lr] = va.z; As[lkq + 3][lr] = va.w;
            const float4 vb = *(const float4*)(W + (size_t)(col0 + lr) * K + k0 + lkq);
            Bs[lkq + 0][lr] = vb.x; Bs[lkq + 1][lr] = vb.y;
            Bs[lkq + 2][lr] = vb.z; Bs[lkq + 3][lr] = vb.w;
        }
        __syncthreads();

#pragma unroll
        for (int k = 0; k < 16; ++k) {
            const float4 a = *(const float4*)&As[k][ty * 4];
            const float4 b = *(const float4*)&Bs[k][tx * 4];
            const float av[4] = {a.x, a.y, a.z, a.w};
            const float bv[4] = {b.x, b.y, b.z, b.w};
#pragma unroll
            for (int i = 0; i < 4; ++i)
#pragma unroll
                for (int j = 0; j < 4; ++j)
                    acc[i][j] = fmaf(av[i], bv[j], acc[i][j]);
        }
        __syncthreads();
    }

    // epilogue
    float bb[4] = {0.f, 0.f, 0.f, 0.f};
    if (bias) {
#pragma unroll
        for (int j = 0; j < 4; ++j) bb[j] = bias[col0 + tx * 4 + j];
    }
#pragma unroll
    for (int i = 0; i < 4; ++i) {
        const int row = row0 + ty * 4 + i;
        if (row < Nrows) {
            float4 o;
            float* op = &o.x;
#pragma unroll
            for (int j = 0; j < 4; ++j) {
                float v = acc[i][j] + bb[j];
                if (apply_silu) v = v / (1.0f + expf(-v));
                op[j] = v;
            }
            *(float4*)(C + (size_t)row * Dout + col0 + tx * 4) = o;
        }
    }
}

// ---------------------------------------------------------------------------
// Stage 3: final projection out[n] = dot(y[n, :], W_out[0, :])   (C == 1)
// One 64-lane wave per node, 4 nodes per 256-thread block.
// ---------------------------------------------------------------------------
__global__ __launch_bounds__(256) void out_proj_kernel(
    const float* __restrict__ Y, const float* __restrict__ W_out,
    float* __restrict__ out, int Nrows)
{
    __shared__ __align__(16) float sw[D_DIM];
    if (threadIdx.x < D_DIM) sw[threadIdx.x] = W_out[threadIdx.x];
    __syncthreads();

    const int wave = threadIdx.x >> 6;
    const int lane = threadIdx.x & 63;
    const int node = blockIdx.x * 4 + wave;
    if (node >= Nrows) return;

    const float4 y = *(const float4*)(Y + (size_t)node * D_DIM + lane * 4);
    const float4 w = *(const float4*)&sw[lane * 4];
    float s = y.x * w.x + y.y * w.y + y.z * w.z + y.w * w.w;

#pragma unroll
    for (int off = 32; off > 0; off >>= 1) s += __shfl_down(s, off, 64);
    if (lane == 0) out[node] = s;
}

// ---------------------------------------------------------------------------
extern "C" void kernel_launch(void* const* d_in, const int* in_sizes, int n_in,
                              void* d_out, int out_size, void* d_ws, size_t ws_size,
                              hipStream_t stream)
{
    const float* x     = (const float*)d_in[0];
    const float* rbf   = (const float*)d_in[1];
    const int*   idx   = (const int*)  d_in[2];
    const float* W_rbf = (const float*)d_in[3];
    const float* W_up  = (const float*)d_in[4];
    const float* Ws    = (const float*)d_in[5];
    const float* bs    = (const float*)d_in[6];
    const float* W_out = (const float*)d_in[7];

    const int E = in_sizes[2];          // one int per edge
    const int N = out_size;             // C == 1 -> out_size == N

    // workspace layout (fp32): agg [N,H] | bufA [N,D] | bufB [N,D]
    float* agg  = (float*)d_ws;
    float* bufA = agg  + (size_t)N * H_DIM;
    float* bufB = bufA + (size_t)N * D_DIM;

    hipMemsetAsync(agg, 0, (size_t)N * H_DIM * sizeof(float), stream);

    edge_scatter_kernel<<<dim3((E + 7) / 8), dim3(256), 0, stream>>>(
        x, rbf, idx, W_rbf, agg, E);

    const dim3 gemm_grid((N + 63) / 64, D_DIM / 64);

    // up-projection: [N,128] @ W_up[256,128]^T -> bufA [N,256], no bias/act
    gemm_tn_kernel<<<gemm_grid, dim3(256), 0, stream>>>(
        agg, W_up, nullptr, bufA, N, H_DIM, D_DIM, 0);

    // 3-layer SiLU MLP, ping-pong bufA <-> bufB
    const float* src = bufA;
    float* dst = bufB;
    for (int l = 0; l < L_NUM; ++l) {
        gemm_tn_kernel<<<gemm_grid, dim3(256), 0, stream>>>(
            src, Ws + (size_t)l * D_DIM * D_DIM, bs + (size_t)l * D_DIM,
            dst, N, D_DIM, D_DIM, 1);
        const float* t = dst; dst = (float*)src; src = t;
    }
    // after 3 layers result is in `src` (bufA->bufB->bufA->bufB)

    out_proj_kernel<<<dim3((N + 3) / 4), dim3(256), 0, stream>>>(
        src, W_out, (float*)d_out, N);
}

// Round 2
// 1141.387 us; speedup vs baseline: 1.1782x; 1.1782x over previous
//
#include <hip/hip_runtime.h>
#include <hip/hip_bf16.h>
#include <math.h>

// Problem constants (fixed by the reference setup):
//   E = 1,000,000 edges, N = 50,000 nodes, R = 6, H = 128, D = 256, C = 1, L = 3
#define H_DIM 128
#define R_DIM 6
#define D_DIM 256
#define L_NUM 3

typedef __attribute__((ext_vector_type(8))) __bf16 bf16x8;
typedef __attribute__((ext_vector_type(4))) __bf16 bf16x4;
typedef __attribute__((ext_vector_type(2))) __bf16 bf16x2;
typedef __attribute__((ext_vector_type(4))) float  f32x4;

// ---------------------------------------------------------------------------
// f32 -> bf16 conversion (weights)
// ---------------------------------------------------------------------------
__global__ __launch_bounds__(256) void cvt_bf16_kernel(
    const float* __restrict__ src, __bf16* __restrict__ dst, int n)
{
    int i = blockIdx.x * 256 + threadIdx.x;
    if (i < n) dst[i] = (__bf16)src[i];
}

// ---------------------------------------------------------------------------
// CSR build step 1: degree histogram (1M atomics on 50k L2-resident ints)
// ---------------------------------------------------------------------------
__global__ __launch_bounds__(256) void hist_kernel(
    const int* __restrict__ idx, int* __restrict__ hist, int E)
{
    int e = blockIdx.x * 256 + threadIdx.x;
    if (e < E) atomicAdd(&hist[idx[e]], 1);
}

// ---------------------------------------------------------------------------
// CSR build step 2: exclusive scan of the histogram (single workgroup,
// 1024 threads = 16 waves, wave-shfl scan + cross-wave LDS scan, reg carry).
// Writes offsets[0..N] and a working copy into cursor[0..N-1].
// ---------------------------------------------------------------------------
__global__ __launch_bounds__(1024) void scan_kernel(
    const int* __restrict__ hist, int* __restrict__ offsets,
    int* __restrict__ cursor, int N)
{
    __shared__ int wsum[16];
    const int lane = threadIdx.x & 63;
    const int wid  = threadIdx.x >> 6;
    int carry = 0;  // identical in every thread

    for (int base = 0; base < N; base += 1024) {
        const int i = base + (int)threadIdx.x;
        const int v = (i < N) ? hist[i] : 0;

        // inclusive scan within the wave
        int incl = v;
#pragma unroll
        for (int off = 1; off < 64; off <<= 1) {
            int t = __shfl_up(incl, off, 64);
            if (lane >= off) incl += t;
        }
        if (lane == 63) wsum[wid] = incl;
        __syncthreads();

        // scan the 16 wave totals (lanes 0..15 of wave 0)
        if (threadIdx.x < 16) {
            int s = wsum[threadIdx.x];
#pragma unroll
            for (int off = 1; off < 16; off <<= 1) {
                int t = __shfl_up(s, off, 64);
                if ((int)threadIdx.x >= off) s += t;
            }
            wsum[threadIdx.x] = s;  // inclusive
        }
        __syncthreads();

        const int wprefix = (wid > 0) ? wsum[wid - 1] : 0;
        const int total   = wsum[15];
        const int excl    = carry + wprefix + (incl - v);
        if (i < N) { offsets[i] = excl; cursor[i] = excl; }
        carry += total;
        __syncthreads();  // protect wsum before next chunk
    }
    if (threadIdx.x == 0) offsets[N] = carry;  // == E
}

// ---------------------------------------------------------------------------
// CSR build step 3: scatter edge ids into per-node slots.
// ---------------------------------------------------------------------------
__global__ __launch_bounds__(256) void scatter_kernel(
    const int* __restrict__ idx, int* __restrict__ cursor,
    int* __restrict__ eid, int E)
{
    int e = blockIdx.x * 256 + threadIdx.x;
    if (e < E) {
        int pos = atomicAdd(&cursor[idx[e]], 1);
        eid[pos] = e;
    }
}

// ---------------------------------------------------------------------------
// Edge gather: one 64-lane wave per node, 2 h-columns per lane.
//   agg[n, h] = sum_{e in edges(n)} (rbf[e] . W_rbf[h]) * x[e, h]   -> bf16
// No atomics, reads are fully coalesced (512 B per x row).
// ---------------------------------------------------------------------------
__global__ __launch_bounds__(256) void gather_kernel(
    const float* __restrict__ x, const float* __restrict__ rbf,
    const int* __restrict__ eid, const int* __restrict__ offsets,
    const float* __restrict__ W_rbf, __bf16* __restrict__ agg, int Nn)
{
    __shared__ float sW[H_DIM * R_DIM];
    for (int t = threadIdx.x; t < H_DIM * R_DIM; t += 256) sW[t] = W_rbf[t];
    __syncthreads();

    const int wave = threadIdx.x >> 6;
    const int lane = threadIdx.x & 63;
    const int node = blockIdx.x * 4 + wave;
    if (node >= Nn) return;

    const int h0 = lane * 2;
    float w0[R_DIM], w1[R_DIM];
#pragma unroll
    for (int r = 0; r < R_DIM; ++r) {
        w0[r] = sW[h0 * R_DIM + r];
        w1[r] = sW[(h0 + 1) * R_DIM + r];
    }

    const int beg = offsets[node];
    const int end = offsets[node + 1];
    float a0 = 0.f, a1 = 0.f;
    for (int j = beg; j < end; ++j) {
        const int e = eid[j];
        const float2 xv = *(const float2*)(x + (size_t)e * H_DIM + h0);
        const float* rp = rbf + (size_t)e * R_DIM;
        float g0 = rp[0] * w0[0] + rp[1] * w0[1] + rp[2] * w0[2]
                 + rp[3] * w0[3] + rp[4] * w0[4] + rp[5] * w0[5];
        float g1 = rp[0] * w1[0] + rp[1] * w1[1] + rp[2] * w1[2]
                 + rp[3] * w1[3] + rp[4] * w1[4] + rp[5] * w1[5];
        a0 = fmaf(g0, xv.x, a0);
        a1 = fmaf(g1, xv.y, a1);
    }
    bf16x2 o; o[0] = (__bf16)a0; o[1] = (__bf16)a1;
    *(bf16x2*)(agg + (size_t)node * H_DIM + h0) = o;
}

// ---------------------------------------------------------------------------
// bf16 MFMA GEMM:  C[n, d] = act( A[n, :K] . W[d, :K] + bias[d] )
//   A: [Nrows, K] bf16 row-major; W: [256, K] bf16 row-major (torch layout);
//   C: [Nrows, 256] bf16. 256 threads = 4 waves, 128x128 block tile,
//   64x64 per wave = 4x4 mfma_f32_16x16x32_bf16 subtiles. No LDS, no
//   barriers: A/B fragments are 16 B per-lane global loads (W is L2-hot,
//   A lines are consumed exactly once per block).
// Fragment layouts (verified m89/m91/m120):
//   A: m = lane&15, k = (lane>>4)*8 + j     B(^T): n = lane&15, k = (lane>>4)*8 + j
//   D: n = lane&15, m = (lane>>4)*4 + reg
// ---------------------------------------------------------------------------
__global__ __launch_bounds__(256) void gemm_bf16_kernel(
    const __bf16* __restrict__ A, const __bf16* __restrict__ W,
    const float* __restrict__ bias, __bf16* __restrict__ C,
    int Nrows, int K, int apply_silu)
{
    const int lane = threadIdx.x & 63;
    const int l16  = lane & 15;
    const int quad = lane >> 4;
    const int wm   = (threadIdx.x >> 6) & 1;   // wave row within block
    const int wn   = (threadIdx.x >> 7);       // wave col within block
    const int row0 = blockIdx.x * 128 + wm * 64;
    const int col0 = blockIdx.y * 128 + wn * 64;

    const __bf16* aptr[4];
    const __bf16* bptr[4];
#pragma unroll
    for (int mi = 0; mi < 4; ++mi) {
        int r = row0 + mi * 16 + l16;
        if (r > Nrows - 1) r = Nrows - 1;          // clamp; stores masked below
        aptr[mi] = A + (size_t)r * K + quad * 8;
    }
#pragma unroll
    for (int ni = 0; ni < 4; ++ni) {
        int c = col0 + ni * 16 + l16;              // Dout=256 divides grid: no OOB
        bptr[ni] = W + (size_t)c * K + quad * 8;
    }

    f32x4 acc[4][4] = {};
    for (int k0 = 0; k0 < K; k0 += 32) {
        bf16x8 af[4], bfr[4];
#pragma unroll
        for (int mi = 0; mi < 4; ++mi) af[mi]  = *(const bf16x8*)(aptr[mi] + k0);
#pragma unroll
        for (int ni = 0; ni < 4; ++ni) bfr[ni] = *(const bf16x8*)(bptr[ni] + k0);
#pragma unroll
        for (int mi = 0; mi < 4; ++mi)
#pragma unroll
            for (int ni = 0; ni < 4; ++ni)
                acc[mi][ni] = __builtin_amdgcn_mfma_f32_16x16x32_bf16(
                    af[mi], bfr[ni], acc[mi][ni], 0, 0, 0);
    }

    // epilogue: bias + SiLU + bf16 store
#pragma unroll
    for (int ni = 0; ni < 4; ++ni) {
        const int colg = col0 + ni * 16 + l16;
        const float bb = bias ? bias[colg] : 0.f;
#pragma unroll
        for (int mi = 0; mi < 4; ++mi) {
#pragma unroll
            for (int reg = 0; reg < 4; ++reg) {
                const int rowg = row0 + mi * 16 + quad * 4 + reg;
                if (rowg < Nrows) {
                    float v = acc[mi][ni][reg] + bb;
                    if (apply_silu) v = v / (1.f + __expf(-v));
                    C[(size_t)rowg * D_DIM + colg] = (__bf16)v;
                }
            }
        }
    }
}

// ---------------------------------------------------------------------------
// Final projection: out[n] = y[n, :] . W_out[0, :]   (C == 1), f32 output.
// ---------------------------------------------------------------------------
__global__ __launch_bounds__(256) void out_proj_kernel(
    const __bf16* __restrict__ Y, const __bf16* __restrict__ wout,
    float* __restrict__ out, int Nrows)
{
    __shared__ float sw[D_DIM];
    if (threadIdx.x < D_DIM) sw[threadIdx.x] = (float)wout[threadIdx.x];
    __syncthreads();

    const int wave = threadIdx.x >> 6;
    const int lane = threadIdx.x & 63;
    const int node = blockIdx.x * 4 + wave;
    if (node >= Nrows) return;

    const bf16x4 y = *(const bf16x4*)(Y + (size_t)node * D_DIM + lane * 4);
    float s = (float)y[0] * sw[lane * 4 + 0] + (float)y[1] * sw[lane * 4 + 1]
            + (float)y[2] * sw[lane * 4 + 2] + (float)y[3] * sw[lane * 4 + 3];
#pragma unroll
    for (int off = 32; off > 0; off >>= 1) s += __shfl_down(s, off, 64);
    if (lane == 0) out[node] = s;
}

// ---------------------------------------------------------------------------
extern "C" void kernel_launch(void* const* d_in, const int* in_sizes, int n_in,
                              void* d_out, int out_size, void* d_ws, size_t ws_size,
                              hipStream_t stream)
{
    const float* x     = (const float*)d_in[0];
    const float* rbf   = (const float*)d_in[1];
    const int*   idx   = (const int*)  d_in[2];
    const float* W_rbf = (const float*)d_in[3];
    const float* W_up  = (const float*)d_in[4];
    const float* Ws    = (const float*)d_in[5];
    const float* bs    = (const float*)d_in[6];
    const float* W_out = (const float*)d_in[7];

    const int E = in_sizes[2];
    const int N = out_size;             // C == 1

    // ---- workspace layout (all 256B-aligned) ----
    char* w = (char*)d_ws;
    int* hist    = (int*)w;  w += 256 * 1024;                 // N ints
    int* offsets = (int*)w;  w += 256 * 1024;                 // N+1 ints
    int* cursor  = (int*)w;  w += 256 * 1024;                 // N ints
    int* eid     = (int*)w;  w += 4 * 1024 * 1024 + 65536;    // E ints
    __bf16* wup  = (__bf16*)w; w += 65536;                    // 256x128
    __bf16* wsb  = (__bf16*)w; w += 393216;                   // 3x256x256
    __bf16* wout = (__bf16*)w; w += 1024;                     // 256
    __bf16* agg  = (__bf16*)w; w += 13 * 1024 * 1024;         // N x 128
    __bf16* actA = (__bf16*)w; w += 26 * 1024 * 1024;         // N x 256
    __bf16* actB = (__bf16*)w; w += 26 * 1024 * 1024;         // N x 256

    // ---- weight conversion (tiny) ----
    cvt_bf16_kernel<<<dim3((D_DIM * H_DIM + 255) / 256), 256, 0, stream>>>(W_up, wup, D_DIM * H_DIM);
    cvt_bf16_kernel<<<dim3((L_NUM * D_DIM * D_DIM + 255) / 256), 256, 0, stream>>>(Ws, wsb, L_NUM * D_DIM * D_DIM);
    cvt_bf16_kernel<<<dim3(1), 256, 0, stream>>>(W_out, wout, D_DIM);

    // ---- CSR build ----
    hipMemsetAsync(hist, 0, (size_t)N * sizeof(int), stream);
    hist_kernel<<<dim3((E + 255) / 256), 256, 0, stream>>>(idx, hist, E);
    scan_kernel<<<dim3(1), 1024, 0, stream>>>(hist, offsets, cursor, N);
    scatter_kernel<<<dim3((E + 255) / 256), 256, 0, stream>>>(idx, cursor, eid, E);

    // ---- edge gather (no atomics) ----
    gather_kernel<<<dim3((N + 3) / 4), 256, 0, stream>>>(
        x, rbf, eid, offsets, W_rbf, agg, N);

    // ---- MFMA GEMM stack ----
    const dim3 ggrid((N + 127) / 128, D_DIM / 128);
    gemm_bf16_kernel<<<ggrid, 256, 0, stream>>>(agg,  wup,               nullptr,      actA, N, H_DIM, 0);
    gemm_bf16_kernel<<<ggrid, 256, 0, stream>>>(actA, wsb,               bs,           actB, N, D_DIM, 1);
    gemm_bf16_kernel<<<ggrid, 256, 0, stream>>>(actB, wsb + D_DIM*D_DIM, bs + D_DIM,   actA, N, D_DIM, 1);
    gemm_bf16_kernel<<<ggrid, 256, 0, stream>>>(actA, wsb + 2*D_DIM*D_DIM, bs + 2*D_DIM, actB, N, D_DIM, 1);

    // ---- final projection ----
    out_proj_kernel<<<dim3((N + 3) / 4), 256, 0, stream>>>(actB, wout, (float*)d_out, N);
}

// Round 3
// 1092.085 us; speedup vs baseline: 1.2314x; 1.0451x over previous
//
#include <hip/hip_runtime.h>
#include <hip/hip_bf16.h>
#include <math.h>

// Problem constants (fixed by the reference setup):
//   E = 1,000,000 edges, N = 50,000 nodes, R = 6, H = 128, D = 256, C = 1, L = 3
#define H_DIM 128
#define R_DIM 6
#define D_DIM 256
#define L_NUM 3

typedef __attribute__((ext_vector_type(8))) __bf16 bf16x8;
typedef __attribute__((ext_vector_type(4))) __bf16 bf16x4;
typedef __attribute__((ext_vector_type(2))) __bf16 bf16x2;
typedef __attribute__((ext_vector_type(4))) float  f32x4;

// ---------------------------------------------------------------------------
// Weight swizzle: f32 [Dout, K] row-major  ->  bf16 fragment-order layout so a
// GEMM wave's B-fragment load is 64 lanes x 16 B fully contiguous (1 KB).
//   Wsw[((cg*(K/32) + kb)*64 + lane)*8 + j] = W[(cg*16 + (lane&15))*K
//                                               + kb*32 + (lane>>4)*8 + j]
// ---------------------------------------------------------------------------
__global__ __launch_bounds__(256) void swizzle_w_kernel(
    const float* __restrict__ W, __bf16* __restrict__ Wsw, int K, int nfrag)
{
    int id = blockIdx.x * 256 + threadIdx.x;          // one thread per (frag, lane)
    if (id >= nfrag * 64) return;
    const int lane = id & 63, f = id >> 6;
    const int KB = K >> 5;
    const int kb = f % KB, cg = f / KB;
    const int row = cg * 16 + (lane & 15);
    const int col = kb * 32 + (lane >> 4) * 8;
    const float* src = W + (size_t)row * K + col;
    __bf16* dst = Wsw + (size_t)id * 8;
#pragma unroll
    for (int j = 0; j < 8; ++j) dst[j] = (__bf16)src[j];
}

__global__ __launch_bounds__(256) void cvt_bf16_kernel(
    const float* __restrict__ src, __bf16* __restrict__ dst, int n)
{
    int i = blockIdx.x * 256 + threadIdx.x;
    if (i < n) dst[i] = (__bf16)src[i];
}

// ---------------------------------------------------------------------------
// CSR build
// ---------------------------------------------------------------------------
__global__ __launch_bounds__(256) void hist_kernel(
    const int* __restrict__ idx, int* __restrict__ hist, int E)
{
    int e = blockIdx.x * 256 + threadIdx.x;
    if (e < E) atomicAdd(&hist[idx[e]], 1);
}

// hierarchical exclusive scan: 1024 elems / block (4 per thread)
__global__ __launch_bounds__(256) void scan1_kernel(
    const int* __restrict__ hist, int* __restrict__ part,
    int* __restrict__ bsum, int N)
{
    __shared__ int wsum[4];
    const int base = blockIdx.x * 1024;
    const int tid = threadIdx.x, lane = tid & 63, w = tid >> 6;

    int v[4]; int s = 0;
#pragma unroll
    for (int c = 0; c < 4; ++c) {
        int i = base + tid * 4 + c;
        v[c] = (i < N) ? hist[i] : 0;
        s += v[c];
    }
    int incl = s;
#pragma unroll
    for (int off = 1; off < 64; off <<= 1) {
        int t = __shfl_up(incl, off, 64);
        if (lane >= off) incl += t;
    }
    if (lane == 63) wsum[w] = incl;
    __syncthreads();
    int wpre = 0;
    for (int k = 0; k < w; ++k) wpre += wsum[k];
    int run = wpre + incl - s;   // exclusive prefix of this thread's first elem
#pragma unroll
    for (int c = 0; c < 4; ++c) {
        int i = base + tid * 4 + c;
        if (i < N) part[i] = run;
        run += v[c];
    }
    if (tid == 255) bsum[blockIdx.x] = wpre + incl;   // block total
}

__global__ __launch_bounds__(64) void scan2_kernel(
    const int* __restrict__ bsum, int* __restrict__ bofs, int nb,
    int* __restrict__ offsets, int N)
{
    const int lane = threadIdx.x;
    int v = (lane < nb) ? bsum[lane] : 0;
    int incl = v;
#pragma unroll
    for (int off = 1; off < 64; off <<= 1) {
        int t = __shfl_up(incl, off, 64);
        if (lane >= off) incl += t;
    }
    if (lane < nb) bofs[lane] = incl - v;
    if (lane == 63) offsets[N] = incl;                // == E
}

__global__ __launch_bounds__(256) void scan3_kernel(
    const int* __restrict__ part, const int* __restrict__ bofs,
    int* __restrict__ offsets, int* __restrict__ cursor, int N)
{
    int i = blockIdx.x * 256 + threadIdx.x;
    if (i < N) {
        int o = part[i] + bofs[i >> 10];
        offsets[i] = o;
        cursor[i] = o;
    }
}

__global__ __launch_bounds__(256) void scatter_kernel(
    const int* __restrict__ idx, int* __restrict__ cursor,
    int* __restrict__ eid, int E)
{
    int e = blockIdx.x * 256 + threadIdx.x;
    if (e < E) {
        int pos = atomicAdd(&cursor[idx[e]], 1);
        eid[pos] = e;
    }
}

// ---------------------------------------------------------------------------
// Edge gather, software-pipelined: one wave per node, 2 h-columns per lane.
//   agg[n, h] = sum_{e in edges(n)} (rbf[e] . W_rbf[h]) * x[e, h]   -> bf16
// ---------------------------------------------------------------------------
__global__ __launch_bounds__(256) void gather_kernel(
    const float* __restrict__ x, const float* __restrict__ rbf,
    const int* __restrict__ eid, const int* __restrict__ offsets,
    const float* __restrict__ W_rbf, __bf16* __restrict__ agg, int Nn)
{
    __shared__ float sW[H_DIM * R_DIM];
    for (int t = threadIdx.x; t < H_DIM * R_DIM; t += 256) sW[t] = W_rbf[t];
    __syncthreads();

    const int wave = threadIdx.x >> 6;
    const int lane = threadIdx.x & 63;
    const int node = blockIdx.x * 4 + wave;
    if (node >= Nn) return;

    const int h0 = lane * 2;
    float w0[R_DIM], w1[R_DIM];
#pragma unroll
    for (int r = 0; r < R_DIM; ++r) {
        w0[r] = sW[h0 * R_DIM + r];
        w1[r] = sW[(h0 + 1) * R_DIM + r];
    }

    const int beg = offsets[node];
    const int end = offsets[node + 1];
    float a0 = 0.f, a1 = 0.f;

    float2 xv_c = {0, 0}, r01_c = {0, 0}, r23_c = {0, 0}, r45_c = {0, 0};
    int e_c = 0;
    if (beg < end) {
        e_c = eid[beg];
        xv_c  = *(const float2*)(x + (size_t)e_c * H_DIM + h0);
        const float2* rp = (const float2*)(rbf + (size_t)e_c * R_DIM);
        r01_c = rp[0]; r23_c = rp[1]; r45_c = rp[2];
    }
    for (int j = beg; j < end; ++j) {
        // prefetch next edge while computing current
        const int e_n = (j + 1 < end) ? eid[j + 1] : e_c;
        const float2 xv_n = *(const float2*)(x + (size_t)e_n * H_DIM + h0);
        const float2* rpn = (const float2*)(rbf + (size_t)e_n * R_DIM);
        const float2 r01_n = rpn[0], r23_n = rpn[1], r45_n = rpn[2];

        float g0 = r01_c.x * w0[0] + r01_c.y * w0[1] + r23_c.x * w0[2]
                 + r23_c.y * w0[3] + r45_c.x * w0[4] + r45_c.y * w0[5];
        float g1 = r01_c.x * w1[0] + r01_c.y * w1[1] + r23_c.x * w1[2]
                 + r23_c.y * w1[3] + r45_c.x * w1[4] + r45_c.y * w1[5];
        a0 = fmaf(g0, xv_c.x, a0);
        a1 = fmaf(g1, xv_c.y, a1);

        xv_c = xv_n; r01_c = r01_n; r23_c = r23_n; r45_c = r45_n;
    }
    bf16x2 o; o[0] = (__bf16)a0; o[1] = (__bf16)a1;
    *(bf16x2*)(agg + (size_t)node * H_DIM + h0) = o;
}

// ---------------------------------------------------------------------------
// bf16 MFMA GEMM (m97-style):  C[n, d] = act( A[n, :K] . W[d, :K] + bias[d] )
//   A: [Nrows, K] bf16 row-major.  Wsw: fragment-swizzled weights (see above).
//   128x256-col coverage per grid: 128x128 tile / block, 4 waves (2x2),
//   64x64 per wave = 4x4 mfma_f32_16x16x32_bf16.  A staged to LDS via
//   global_load_lds width 16 (coalesced); A-frags via ds_read_b128; B-frags
//   are contiguous 1 KB loads from Wsw (L2-hot).
// Fragment layouts (verified m89/m91): A: m=lane&15, k=(lane>>4)*8+j.
//   D: n=lane&15, m=(lane>>4)*4+reg.
// ---------------------------------------------------------------------------
__global__ __launch_bounds__(256) void gemm_mfma_kernel(
    const __bf16* __restrict__ A, const __bf16* __restrict__ Wsw,
    const float* __restrict__ bias, __bf16* __restrict__ C,
    int Nrows, int K, int apply_silu)
{
    __shared__ __align__(16) __bf16 As[128 * 32];   // 8 KB: [row][k] dense, 64 B rows
    const int tid  = threadIdx.x;
    const int lane = tid & 63, w = tid >> 6;
    const int l16  = lane & 15, quad = lane >> 4;
    const int wm   = w & 1, wn = w >> 1;
    const int row0 = blockIdx.x * 128;
    const int cg0  = blockIdx.y * 8 + wn * 4;       // 16-col group index base
    const int KB   = K >> 5;

    // staging: 2 instrs/thread; instr i covers LDS bytes [w*1024 + i*4096 + lane*16]
    int srow[2];
#pragma unroll
    for (int i = 0; i < 2; ++i) {
        int r = row0 + w * 16 + i * 64 + (lane >> 2);
        if (r > Nrows - 1) r = Nrows - 1;           // clamp; stores masked below
        srow[i] = r;
    }

    f32x4 acc[4][4] = {};
    for (int kb = 0; kb < KB; ++kb) {
#pragma unroll
        for (int i = 0; i < 2; ++i) {
            const __bf16* gp = A + (size_t)srow[i] * K + kb * 32 + (lane & 3) * 8;
#if defined(__has_builtin) && __has_builtin(__builtin_amdgcn_global_load_lds)
            __builtin_amdgcn_global_load_lds(
                (const __attribute__((address_space(1))) void*)gp,
                (__attribute__((address_space(3))) void*)((char*)As + w * 1024 + i * 4096),
                16, 0, 0);
#else
            *(bf16x8*)((char*)As + w * 1024 + i * 4096 + lane * 16) = *(const bf16x8*)gp;
#endif
        }
        __syncthreads();

        bf16x8 af[4], bfr[4];
#pragma unroll
        for (int mi = 0; mi < 4; ++mi)
            af[mi] = *(const bf16x8*)(As + (wm * 64 + mi * 16 + l16) * 32 + quad * 8);
#pragma unroll
        for (int ni = 0; ni < 4; ++ni)
            bfr[ni] = *(const bf16x8*)(Wsw + (((size_t)(cg0 + ni) * KB + kb) * 64 + lane) * 8);
#pragma unroll
        for (int mi = 0; mi < 4; ++mi)
#pragma unroll
            for (int ni = 0; ni < 4; ++ni)
                acc[mi][ni] = __builtin_amdgcn_mfma_f32_16x16x32_bf16(
                    af[mi], bfr[ni], acc[mi][ni], 0, 0, 0);
        __syncthreads();
    }

    // epilogue: bias + SiLU + bf16 store
#pragma unroll
    for (int ni = 0; ni < 4; ++ni) {
        const int colg = (cg0 + ni) * 16 + l16;
        const float bb = bias ? bias[colg] : 0.f;
#pragma unroll
        for (int mi = 0; mi < 4; ++mi) {
#pragma unroll
            for (int reg = 0; reg < 4; ++reg) {
                const int rowg = row0 + wm * 64 + mi * 16 + quad * 4 + reg;
                if (rowg < Nrows) {
                    float v = acc[mi][ni][reg] + bb;
                    if (apply_silu) v = v / (1.f + __expf(-v));
                    C[(size_t)rowg * D_DIM + colg] = (__bf16)v;
                }
            }
        }
    }
}

// ---------------------------------------------------------------------------
// Final projection: out[n] = y[n, :] . W_out[0, :]   (C == 1), f32 output.
// ---------------------------------------------------------------------------
__global__ __launch_bounds__(256) void out_proj_kernel(
    const __bf16* __restrict__ Y, const __bf16* __restrict__ wout,
    float* __restrict__ out, int Nrows)
{
    __shared__ float sw[D_DIM];
    if (threadIdx.x < D_DIM) sw[threadIdx.x] = (float)wout[threadIdx.x];
    __syncthreads();

    const int wave = threadIdx.x >> 6;
    const int lane = threadIdx.x & 63;
    const int node = blockIdx.x * 4 + wave;
    if (node >= Nrows) return;

    const bf16x4 y = *(const bf16x4*)(Y + (size_t)node * D_DIM + lane * 4);
    float s = (float)y[0] * sw[lane * 4 + 0] + (float)y[1] * sw[lane * 4 + 1]
            + (float)y[2] * sw[lane * 4 + 2] + (float)y[3] * sw[lane * 4 + 3];
#pragma unroll
    for (int off = 32; off > 0; off >>= 1) s += __shfl_down(s, off, 64);
    if (lane == 0) out[node] = s;
}

// ---------------------------------------------------------------------------
extern "C" void kernel_launch(void* const* d_in, const int* in_sizes, int n_in,
                              void* d_out, int out_size, void* d_ws, size_t ws_size,
                              hipStream_t stream)
{
    const float* x     = (const float*)d_in[0];
    const float* rbf   = (const float*)d_in[1];
    const int*   idx   = (const int*)  d_in[2];
    const float* W_rbf = (const float*)d_in[3];
    const float* W_up  = (const float*)d_in[4];
    const float* Ws    = (const float*)d_in[5];
    const float* bs    = (const float*)d_in[6];
    const float* W_out = (const float*)d_in[7];

    const int E = in_sizes[2];
    const int N = out_size;             // C == 1

    // ---- workspace layout ----
    char* w = (char*)d_ws;
    int* hist    = (int*)w;  w += 256 * 1024;                 // N ints
    int* part    = (int*)w;  w += 256 * 1024;                 // N ints
    int* offsets = (int*)w;  w += 256 * 1024;                 // N+1 ints
    int* cursor  = (int*)w;  w += 256 * 1024;                 // N ints
    int* bsum    = (int*)w;  w += 1024;                       // <=64 ints
    int* bofs    = (int*)w;  w += 1024;
    int* eid     = (int*)w;  w += 4 * 1024 * 1024 + 65536;    // E ints
    __bf16* wsw_up = (__bf16*)w; w += 65536;                  // 256x128 bf16
    __bf16* wsw_l  = (__bf16*)w; w += 393216;                 // 3x256x256 bf16
    __bf16* wout   = (__bf16*)w; w += 1024;                   // 256 bf16
    __bf16* agg    = (__bf16*)w; w += 13 * 1024 * 1024;       // N x 128 bf16
    __bf16* actA   = (__bf16*)w; w += 26 * 1024 * 1024;       // N x 256 bf16
    __bf16* actB   = (__bf16*)w; w += 26 * 1024 * 1024;       // N x 256 bf16

    // ---- weight prep (tiny) ----
    {
        const int nfU = (D_DIM / 16) * (H_DIM / 32);          // 64 frags
        swizzle_w_kernel<<<dim3((nfU * 64 + 255) / 256), 256, 0, stream>>>(
            W_up, wsw_up, H_DIM, nfU);
        const int nfL = (D_DIM / 16) * (D_DIM / 32);          // 128 frags/layer
        for (int l = 0; l < L_NUM; ++l)
            swizzle_w_kernel<<<dim3((nfL * 64 + 255) / 256), 256, 0, stream>>>(
                Ws + (size_t)l * D_DIM * D_DIM, wsw_l + (size_t)l * D_DIM * D_DIM,
                D_DIM, nfL);
        cvt_bf16_kernel<<<dim3(1), 256, 0, stream>>>(W_out, wout, D_DIM);
    }

    // ---- CSR build ----
    hipMemsetAsync(hist, 0, (size_t)N * sizeof(int), stream);
    hist_kernel<<<dim3((E + 255) / 256), 256, 0, stream>>>(idx, hist, E);
    const int nb = (N + 1023) / 1024;                         // 49
    scan1_kernel<<<dim3(nb), 256, 0, stream>>>(hist, part, bsum, N);
    scan2_kernel<<<dim3(1), 64, 0, stream>>>(bsum, bofs, nb, offsets, N);
    scan3_kernel<<<dim3((N + 255) / 256), 256, 0, stream>>>(part, bofs, offsets, cursor, N);
    scatter_kernel<<<dim3((E + 255) / 256), 256, 0, stream>>>(idx, cursor, eid, E);

    // ---- edge gather (no atomics, pipelined) ----
    gather_kernel<<<dim3((N + 3) / 4), 256, 0, stream>>>(
        x, rbf, eid, offsets, W_rbf, agg, N);

    // ---- MFMA GEMM stack ----
    const dim3 ggrid((N + 127) / 128, D_DIM / 128);
    gemm_mfma_kernel<<<ggrid, 256, 0, stream>>>(agg,  wsw_up, nullptr, actA, N, H_DIM, 0);
    gemm_mfma_kernel<<<ggrid, 256, 0, stream>>>(actA, wsw_l,                         bs,             actB, N, D_DIM, 1);
    gemm_mfma_kernel<<<ggrid, 256, 0, stream>>>(actB, wsw_l + (size_t)D_DIM * D_DIM, bs + D_DIM,     actA, N, D_DIM, 1);
    gemm_mfma_kernel<<<ggrid, 256, 0, stream>>>(actA, wsw_l + (size_t)2 * D_DIM * D_DIM, bs + 2 * D_DIM, actB, N, D_DIM, 1);

    // ---- final projection ----
    out_proj_kernel<<<dim3((N + 3) / 4), 256, 0, stream>>>(actB, wout, (float*)d_out, N);
}